// Round 7
// baseline (854.821 us; speedup 1.0000x reference)
//
#include <hip/hip_runtime.h>
#include <stdint.h>
#include <stddef.h>

#define NN 50000
#define NE 800000
#define DD 128
#define NL 4
#define NG 512
#define NC 10
#define NB 196           // buckets of 256 dest nodes: ceil(50000/256)
#define BCAP 5056        // fixed per-bucket region capacity (mean 4081, huge margin)
#define GPB 49           // p2 extra blocks for gptr: ceil(50000/1024)

using short8 = __attribute__((ext_vector_type(8))) short;
using f32x4  = __attribute__((ext_vector_type(4))) float;

__device__ __forceinline__ float bf2f(unsigned short u) {
  union { unsigned int i; float f; } c; c.i = ((unsigned int)u) << 16; return c.f;
}
__device__ __forceinline__ unsigned short f2bf(float f) {
  union { unsigned int i; float f; } c; c.f = f;
  unsigned int i = c.i;
  return (unsigned short)((i + 0x7FFFu + ((i >> 16) & 1u)) >> 16);
}
__device__ __forceinline__ unsigned int pack2(float a, float b) {
  return (unsigned int)f2bf(a) | ((unsigned int)f2bf(b) << 16);
}
__device__ __forceinline__ void acc8(float* a, uint4 p) {
  a[0] += bf2f((unsigned short)(p.x & 0xffffu)); a[1] += bf2f((unsigned short)(p.x >> 16));
  a[2] += bf2f((unsigned short)(p.y & 0xffffu)); a[3] += bf2f((unsigned short)(p.y >> 16));
  a[4] += bf2f((unsigned short)(p.z & 0xffffu)); a[5] += bf2f((unsigned short)(p.z >> 16));
  a[6] += bf2f((unsigned short)(p.w & 0xffffu)); a[7] += bf2f((unsigned short)(p.w >> 16));
}

// ---------------- p1b v2: place packed edges into FIXED bucket regions.
// LDS-staged, bucket-ordered global writes (R6-proven).
__global__ __launch_bounds__(1024) void p1b_k(const int* __restrict__ erow,
                                              const int* __restrict__ ecol,
                                              int* __restrict__ cursor,
                                              unsigned int* __restrict__ ebuf) {
  __shared__ int lcnt[256], loff[256];    // 196 used, padded to 256 for the scan
  __shared__ int gb[NB];
  __shared__ unsigned int stage[4096];
  __shared__ int gpos[4096];
  int tid = threadIdx.x;
  if (tid < 256) lcnt[tid] = 0;
  __syncthreads();
  int e0 = blockIdx.x * 4096 + tid;
  int bk[4], sl[4]; unsigned int pk[4];
#pragma unroll
  for (int j = 0; j < 4; ++j) {
    int e = e0 + j * 1024;
    bk[j] = -1;
    if (e < NE) {
      int d = ecol[e], s = erow[e];
      bk[j] = d >> 8;
      pk[j] = ((unsigned int)(d & 255) << 16) | (unsigned int)s;
      sl[j] = atomicAdd(&lcnt[bk[j]], 1);
    }
  }
  __syncthreads();
  if (tid < 256) loff[tid] = lcnt[tid];
  __syncthreads();
  for (int off = 1; off < 256; off <<= 1) {
    int v = (tid < 256 && tid >= off) ? loff[tid - off] : 0;
    __syncthreads();
    if (tid < 256) loff[tid] += v;
    __syncthreads();
  }
  if (tid < NB) {
    int c = lcnt[tid];
    gb[tid] = c ? atomicAdd(&cursor[tid], c) : 0;
  }
  __syncthreads();
#pragma unroll
  for (int j = 0; j < 4; ++j)
    if (bk[j] >= 0) {
      int ex = loff[bk[j]] - lcnt[bk[j]] + sl[j];
      stage[ex] = pk[j];
      gpos[ex] = bk[j] * BCAP + gb[bk[j]] + sl[j];
    }
  __syncthreads();
  int total = loff[255];
  for (int i = tid; i < total; i += 1024)
    ebuf[gpos[i]] = stage[i];
}

// ---------------- p2: bucket counting sort + dinv + x->bf16*dinv | gptr | W transpose ----
// NEW: csr_src keeps the PACKED (dest_local<<16 | src) value so flayer can do
// segmented reduction over evenly-split edge ranges.
__global__ __launch_bounds__(1024) void p2_k(const unsigned int* __restrict__ ebuf,
                                             const int* __restrict__ cursor,
                                             const float* __restrict__ x,
                                             const int* __restrict__ batch,
                                             const float* __restrict__ Wc,
                                             int* __restrict__ csr_ptr,
                                             int* __restrict__ csr_end,
                                             int* __restrict__ csr_src,
                                             float* __restrict__ dinv,
                                             unsigned short* __restrict__ xb,
                                             int* __restrict__ gptr,
                                             unsigned short* __restrict__ Wbt) {
  int b = blockIdx.x, tid = threadIdx.x;
  if (b >= NB + GPB) {                   // W conversion role
    int l = b - NB - GPB;
    const float* W = Wc + (size_t)l * DD * DD;
    unsigned short* WT = Wbt + (size_t)l * DD * DD;
    for (int i = tid; i < DD * DD; i += 1024) {
      int n = i >> 7, k = i & 127;
      WT[n * DD + k] = f2bf(W[k * DD + n]);
    }
    return;
  }
  if (b >= NB) {                         // gptr role
    int i = (b - NB) * 1024 + tid;
    if (i >= NN) return;
    int bb = batch[i];
    int bp = (i == 0) ? -1 : batch[i - 1];
    for (int g = bp + 1; g <= bb; ++g) gptr[g] = i;
    if (i == NN - 1) { for (int g = bb + 1; g <= NG; ++g) gptr[g] = NN; }
    return;
  }

  __shared__ unsigned int pr[BCAP];
  __shared__ int srcb[BCAP];
  __shared__ int hist_s[256], scn[256], lcur[256];
  __shared__ float dinv_s[256];
  size_t beg = (size_t)b * BCAP;
  int cnt = cursor[b];
  if (cnt > BCAP) cnt = BCAP;            // safety (never hit)

  if (tid < 256) hist_s[tid] = 0;
  __syncthreads();
  for (int i = tid; i < cnt; i += 1024) {
    unsigned int p = ebuf[beg + i];
    pr[i] = p;
    atomicAdd(&hist_s[p >> 16], 1);
  }
  __syncthreads();
  if (tid < 256) scn[tid] = hist_s[tid];
  __syncthreads();
  for (int off = 1; off < 256; off <<= 1) {
    int v = (tid < 256 && tid >= off) ? scn[tid - off] : 0;
    __syncthreads();
    if (tid < 256) scn[tid] += v;
    __syncthreads();
  }
  if (tid < 256) {
    int ex = scn[tid] - hist_s[tid];
    lcur[tid] = ex;
    int V = b * 256 + tid;
    if (V < NN) {
      csr_ptr[V] = (int)beg + ex;
      csr_end[V] = (int)beg + scn[tid];
      float dv = rsqrtf((float)(hist_s[tid] + 1));
      dinv[V] = dv;
      dinv_s[tid] = dv;
    }
  }
  __syncthreads();
  for (int i = tid; i < cnt; i += 1024) {
    unsigned int p = pr[i];
    int pos = atomicAdd(&lcur[p >> 16], 1);
    srcb[pos] = (int)p;                  // keep PACKED (dloc<<16 | src)
  }
  __syncthreads();
  for (int i = tid; i < cnt; i += 1024) csr_src[beg + i] = srcb[i];

  // x -> bf16 pre-scaled by dinv (row-major)
  for (int i4 = tid; i4 < 256 * 32; i4 += 1024) {
    int vl = i4 >> 5;
    int V = b * 256 + vl;
    if (V < NN) {
      float d = dinv_s[vl];
      int q = i4 & 31;
      f32x4 vx = *((const f32x4*)(x + (size_t)V * DD) + q);
      uint2 o;
      o.x = pack2(vx[0] * d, vx[1] * d);
      o.y = pack2(vx[2] * d, vx[3] * d);
      ((uint2*)(xb + (size_t)V * DD))[q] = o;
    }
  }
}

// ---------------- fused layer v4: segmented-reduction aggregation.
// 16-row tile, edges split EVENLY across 16 waves x 4 lane-groups (64 streams,
// uniform trip counts -> no degree tail). Register accumulate, LDS fp32 atomic
// flush at dest boundaries. Then dinv-scale + bf16 pack + proven MFMA epilogue.
__global__ __launch_bounds__(1024, 8) void flayer_k(
    const unsigned short* __restrict__ hs,
    const unsigned short* __restrict__ Wb,
    const float* __restrict__ bias,
    unsigned short* __restrict__ out,
    const float* __restrict__ dscale,
    const int* __restrict__ csr_ptr,
    const int* __restrict__ csr_end,
    const int* __restrict__ csr_src,
    const float* __restrict__ dinv) {
  __shared__ unsigned short Wt[128][136];   // [n][k] bf16, +8 pad (proven)
  __shared__ float At32[16][128];           // fp32 accumulation tile
  __shared__ unsigned short Atb[16][136];   // bf16 tile for MFMA A-frags

  int tid = threadIdx.x;
  for (int i = tid; i < 128 * 16; i += 1024) {
    int rr = i >> 4, c = i & 15;
    *(uint4*)&Wt[rr][c * 8] = *(const uint4*)(Wb + rr * DD + c * 8);
  }

  int wave = tid >> 6, lane = tid & 63;
  int qg = lane >> 4, r = lane & 15;
  int v0 = blockIdx.x * 16;                // tile rows [v0, v0+16), always < NN
  int tb = v0 & 255;                       // tile base within its bucket
  const uint4* rows = (const uint4*)hs;

  // seed At32 with the self term (row v pre-scaled by dinv[v] already in hs)
  if (qg == 0) {
    uint4 sp = rows[(size_t)(v0 + wave) * 16 + r];
    float s8[8] = {0.f, 0.f, 0.f, 0.f, 0.f, 0.f, 0.f, 0.f};
    acc8(s8, sp);
    *(f32x4*)&At32[wave][r * 8]     = (f32x4){s8[0], s8[1], s8[2], s8[3]};
    *(f32x4*)&At32[wave][r * 8 + 4] = (f32x4){s8[4], s8[5], s8[6], s8[7]};
  }
  __syncthreads();

  // ---- segmented-reduction edge phase ----
  int beg  = csr_ptr[v0];
  int endt = csr_end[v0 + 15];
  int len  = endt - beg;
  int w0 = beg + (int)(((long long)len * wave) >> 4);
  int w1 = beg + (int)(((long long)len * (wave + 1)) >> 4);
  int qlen = w1 - w0;
  int q0 = w0 + (int)(((long long)qlen * qg) >> 2);
  int q1 = w0 + (int)(((long long)qlen * (qg + 1)) >> 2);

  float A[8] = {0.f, 0.f, 0.f, 0.f, 0.f, 0.f, 0.f, 0.f};
  int cur = -1;
  for (int e = q0; e < q1; ++e) {
    unsigned int p = (unsigned int)csr_src[e];
    int dl = (int)(p >> 16) - tb;            // 0..15 within tile
    if (dl != cur) {
      if (cur >= 0) {
#pragma unroll
        for (int j = 0; j < 8; ++j) atomicAdd(&At32[cur][r * 8 + j], A[j]);
      }
      cur = dl;
#pragma unroll
      for (int j = 0; j < 8; ++j) A[j] = 0.f;
    }
    uint4 row = rows[(size_t)(p & 0xffffu) * 16 + r];
    acc8(A, row);
  }
  if (cur >= 0) {
#pragma unroll
    for (int j = 0; j < 8; ++j) atomicAdd(&At32[cur][r * 8 + j], A[j]);
  }
  __syncthreads();

  // ---- dinv scale + bf16 pack (1024 threads x 2 elems = 16x128) ----
  {
    int i4 = tid;                            // 16*64 = 1024 exactly
    int row = i4 >> 6, c2 = (i4 & 63) * 2;
    float dv = dinv[v0 + row];
    unsigned int o = pack2(At32[row][c2] * dv, At32[row][c2 + 1] * dv);
    *(unsigned int*)&Atb[row][c2] = o;
  }
  __syncthreads();

  // ---- GEMM epilogue (R4-proven): waves 0..7, wave w -> cols [w*16, w*16+16) ----
  if (wave < 8) {
    short8 afrag[4];
#pragma unroll
    for (int ks = 0; ks < 4; ++ks)
      afrag[ks] = *(const short8*)&Atb[r][ks * 32 + qg * 8];

    f32x4 acc = (f32x4){0.f, 0.f, 0.f, 0.f};
#pragma unroll
    for (int ks = 0; ks < 4; ++ks) {
      short8 bfrag = *(const short8*)(&Wt[wave * 16 + r][ks * 32 + qg * 8]);
      acc = __builtin_amdgcn_mfma_f32_16x16x32_bf16(afrag[ks], bfrag, acc, 0, 0, 0);
    }

    int orow = v0 + qg * 4;
    int coln = wave * 16 + r;
    float bc = bias[coln];
#pragma unroll
    for (int reg = 0; reg < 4; ++reg) {
      int rr = orow + reg;
      float sc = dscale ? dscale[rr] : 1.f;
      float val = fmaxf(acc[reg] + bc, 0.f) * sc;
      out[(size_t)rr * DD + coln] = f2bf(val);
    }
  }
}

// ---------------- fused pool + MLP head v3: uint4-vectorized pooling ----------------
__global__ __launch_bounds__(512) void poolmlp_k(const unsigned short* __restrict__ h,
                                                 const int* __restrict__ gptr,
                                                 const float* __restrict__ W1,
                                                 const float* __restrict__ b1,
                                                 const float* __restrict__ W2,
                                                 const float* __restrict__ b2,
                                                 const float* __restrict__ W3,
                                                 const float* __restrict__ b3,
                                                 float* __restrict__ out) {
  __shared__ float s_part[8][128];
  __shared__ float s_g[128], s_h1[128], s_h2[64];
  int g = blockIdx.x, tid = threadIdx.x;
  int wave = tid >> 6, lane = tid & 63;
  int qg = lane >> 4, r = lane & 15;
  int beg = gptr[g], end = gptr[g + 1];
  const uint4* rows = (const uint4*)h;

  float A[8] = {0.f, 0.f, 0.f, 0.f, 0.f, 0.f, 0.f, 0.f};
  for (int v = beg + wave * 4 + qg; v < end; v += 32)
    acc8(A, rows[(size_t)v * 16 + r]);
#pragma unroll
  for (int j = 0; j < 8; ++j) {
    A[j] += __shfl_xor(A[j], 16, 64);
    A[j] += __shfl_xor(A[j], 32, 64);
  }
  if (qg == 0) {
    *(f32x4*)&s_part[wave][r * 8]     = (f32x4){A[0], A[1], A[2], A[3]};
    *(f32x4*)&s_part[wave][r * 8 + 4] = (f32x4){A[4], A[5], A[6], A[7]};
  }
  __syncthreads();
  if (tid < 128) {
    float sg = 0.f;
#pragma unroll
    for (int w = 0; w < 8; ++w) sg += s_part[w][tid];
    s_g[tid] = sg;
  }
  __syncthreads();
  if (tid < 128) {
    float a = b1[tid];
    for (int k = 0; k < 128; ++k) a += s_g[k] * W1[k * 128 + tid];
    s_h1[tid] = fmaxf(a, 0.f);
  }
  __syncthreads();
  if (tid < 64) {
    float a = b2[tid];
    for (int k = 0; k < 128; ++k) a += s_h1[k] * W2[k * 64 + tid];
    s_h2[tid] = fmaxf(a, 0.f);
  }
  __syncthreads();
  if (tid < NC) {
    float a = b3[tid];
    for (int k = 0; k < 64; ++k) a += s_h2[k] * W3[k * NC + tid];
    out[g * NC + tid] = a;
  }
}

// ---------------- launch ----------------

extern "C" void kernel_launch(void* const* d_in, const int* in_sizes, int n_in,
                              void* d_out, int out_size, void* d_ws, size_t ws_size,
                              hipStream_t stream) {
  const float* x     = (const float*)d_in[0];
  const int*   ei    = (const int*)d_in[1];
  const int*   batch = (const int*)d_in[2];
  const float* Wc    = (const float*)d_in[3];
  const float* bc    = (const float*)d_in[4];
  const float* W1    = (const float*)d_in[5];
  const float* b1    = (const float*)d_in[6];
  const float* W2    = (const float*)d_in[7];
  const float* b2    = (const float*)d_in[8];
  const float* W3    = (const float*)d_in[9];
  const float* b3    = (const float*)d_in[10];
  float* out = (float*)d_out;

  const int* erow = ei;        // edge_index[0] (source)
  const int* ecol = ei + NE;   // edge_index[1] (dest)

  char* w = (char*)d_ws;
  int*   cursor  = (int*)w;    w += NB * 4;                 // memset 0 (784 B)
  int*   csr_ptr = (int*)w;    w += (size_t)(NN + 4) * 4;
  int*   csr_end = (int*)w;    w += (size_t)(NN + 4) * 4;
  int*   gptr    = (int*)w;    w += (NG + 4) * 4;
  int*   csr_src = (int*)w;    w += (size_t)NB * BCAP * 4;  // fixed-base regions
  float* dinv    = (float*)w;  w += (size_t)NN * 4;
  w = (char*)(((uintptr_t)w + 255) & ~(uintptr_t)255);
  unsigned short* Wbt  = (unsigned short*)w; w += (size_t)NL * DD * DD * 2;
  unsigned short* xb   = (unsigned short*)w; w += (size_t)NN * DD * 2;
  unsigned short* hA   = (unsigned short*)w; w += (size_t)NN * DD * 2;
  unsigned short* hB   = (unsigned short*)w; w += (size_t)NN * DD * 2;
  unsigned int* ebuf = (unsigned int*)hA;    // alias: 196*BCAP*4 = 3.96MB < 12.8MB;
                                             // dead before layer-0 writes hA

  hipMemsetAsync(cursor, 0, NB * 4, stream);

  p1b_k<<<NB, 1024, 0, stream>>>(erow, ecol, cursor, ebuf);
  p2_k <<<NB + GPB + NL, 1024, 0, stream>>>(ebuf, cursor, x, batch, Wc, csr_ptr,
                                            csr_end, csr_src, dinv, xb, gptr, Wbt);

  const int fGrid = NN / 16;   // 3125, exact

  for (int l = 0; l < NL; ++l) {
    const unsigned short* hin = (l == 0) ? xb : ((l & 1) ? hA : hB);
    unsigned short* dst = (l & 1) ? hB : hA;
    const float* dsc = (l == NL - 1) ? nullptr : dinv;
    flayer_k<<<fGrid, 1024, 0, stream>>>(hin, Wbt + (size_t)l * DD * DD,
                                         bc + (size_t)l * DD, dst, dsc,
                                         csr_ptr, csr_end, csr_src, dinv);
  }

  poolmlp_k<<<NG, 512, 0, stream>>>(hB, gptr, W1, b1, W2, b2, W3, b3, out);

  (void)in_sizes; (void)n_in; (void)out_size; (void)ws_size;
}

// Round 9
// 601.955 us; speedup vs baseline: 1.4201x; 1.4201x over previous
//
#include <hip/hip_runtime.h>
#include <stdint.h>
#include <stddef.h>

#define NN 50000
#define NE 800000
#define DD 128
#define NL 4
#define NG 512
#define NC 10
#define NB 196           // buckets of 256 dest nodes: ceil(50000/256)
#define BCAP 5056        // fixed per-bucket region capacity (mean 4081, huge margin)
#define GPB 49           // p2 extra blocks for gptr / p3 grid: ceil(50000/1024)

using short8 = __attribute__((ext_vector_type(8))) short;
using f32x4  = __attribute__((ext_vector_type(4))) float;

__device__ __forceinline__ float bf2f(unsigned short u) {
  union { unsigned int i; float f; } c; c.i = ((unsigned int)u) << 16; return c.f;
}
__device__ __forceinline__ unsigned short f2bf(float f) {
  union { unsigned int i; float f; } c; c.f = f;
  unsigned int i = c.i;
  return (unsigned short)((i + 0x7FFFu + ((i >> 16) & 1u)) >> 16);
}
__device__ __forceinline__ unsigned int pack2(float a, float b) {
  return (unsigned int)f2bf(a) | ((unsigned int)f2bf(b) << 16);
}
__device__ __forceinline__ void acc8(float* a, uint4 p) {
  a[0] += bf2f((unsigned short)(p.x & 0xffffu)); a[1] += bf2f((unsigned short)(p.x >> 16));
  a[2] += bf2f((unsigned short)(p.y & 0xffffu)); a[3] += bf2f((unsigned short)(p.y >> 16));
  a[4] += bf2f((unsigned short)(p.z & 0xffffu)); a[5] += bf2f((unsigned short)(p.z >> 16));
  a[6] += bf2f((unsigned short)(p.w & 0xffffu)); a[7] += bf2f((unsigned short)(p.w >> 16));
}

// ---------------- p1b v2 (R6-proven): LDS-staged, bucket-ordered edge placement ------
__global__ __launch_bounds__(1024) void p1b_k(const int* __restrict__ erow,
                                              const int* __restrict__ ecol,
                                              int* __restrict__ cursor,
                                              unsigned int* __restrict__ ebuf) {
  __shared__ int lcnt[256], loff[256];    // 196 used, padded to 256 for the scan
  __shared__ int gb[NB];
  __shared__ unsigned int stage[4096];
  __shared__ int gpos[4096];
  int tid = threadIdx.x;
  if (tid < 256) lcnt[tid] = 0;
  __syncthreads();
  int e0 = blockIdx.x * 4096 + tid;
  int bk[4], sl[4]; unsigned int pk[4];
#pragma unroll
  for (int j = 0; j < 4; ++j) {
    int e = e0 + j * 1024;
    bk[j] = -1;
    if (e < NE) {
      int d = ecol[e], s = erow[e];
      bk[j] = d >> 8;
      pk[j] = ((unsigned int)(d & 255) << 16) | (unsigned int)s;
      sl[j] = atomicAdd(&lcnt[bk[j]], 1);
    }
  }
  __syncthreads();
  if (tid < 256) loff[tid] = lcnt[tid];
  __syncthreads();
  for (int off = 1; off < 256; off <<= 1) {
    int v = (tid < 256 && tid >= off) ? loff[tid - off] : 0;
    __syncthreads();
    if (tid < 256) loff[tid] += v;
    __syncthreads();
  }
  if (tid < NB) {
    int c = lcnt[tid];
    gb[tid] = c ? atomicAdd(&cursor[tid], c) : 0;
  }
  __syncthreads();
#pragma unroll
  for (int j = 0; j < 4; ++j)
    if (bk[j] >= 0) {
      int ex = loff[bk[j]] - lcnt[bk[j]] + sl[j];
      stage[ex] = pk[j];
      gpos[ex] = bk[j] * BCAP + gb[bk[j]] + sl[j];
    }
  __syncthreads();
  int total = loff[255];
  for (int i = tid; i < total; i += 1024)
    ebuf[gpos[i]] = stage[i];
}

// ---------------- p2 (R6 + deg/dhist outputs) ----------------
__global__ __launch_bounds__(1024) void p2_k(const unsigned int* __restrict__ ebuf,
                                             const int* __restrict__ cursor,
                                             const float* __restrict__ x,
                                             const int* __restrict__ batch,
                                             const float* __restrict__ Wc,
                                             int* __restrict__ csr_ptr,
                                             int* __restrict__ csr_end,
                                             int* __restrict__ csr_src,
                                             float* __restrict__ dinv,
                                             unsigned short* __restrict__ xb,
                                             int* __restrict__ gptr,
                                             unsigned short* __restrict__ Wbt,
                                             int* __restrict__ deg,
                                             int* __restrict__ dhist) {
  int b = blockIdx.x, tid = threadIdx.x;
  if (b >= NB + GPB) {                   // W conversion role
    int l = b - NB - GPB;
    const float* W = Wc + (size_t)l * DD * DD;
    unsigned short* WT = Wbt + (size_t)l * DD * DD;
    for (int i = tid; i < DD * DD; i += 1024) {
      int n = i >> 7, k = i & 127;
      WT[n * DD + k] = f2bf(W[k * DD + n]);
    }
    return;
  }
  if (b >= NB) {                         // gptr role
    int i = (b - NB) * 1024 + tid;
    if (i >= NN) return;
    int bb = batch[i];
    int bp = (i == 0) ? -1 : batch[i - 1];
    for (int g = bp + 1; g <= bb; ++g) gptr[g] = i;
    if (i == NN - 1) { for (int g = bb + 1; g <= NG; ++g) gptr[g] = NN; }
    return;
  }

  __shared__ unsigned int pr[BCAP];
  __shared__ int srcb[BCAP];
  __shared__ int hist_s[256], scn[256], lcur[256];
  __shared__ float dinv_s[256];
  size_t beg = (size_t)b * BCAP;
  int cnt = cursor[b];
  if (cnt > BCAP) cnt = BCAP;            // safety (never hit)

  if (tid < 256) hist_s[tid] = 0;
  __syncthreads();
  for (int i = tid; i < cnt; i += 1024) {
    unsigned int p = ebuf[beg + i];
    pr[i] = p;
    atomicAdd(&hist_s[p >> 16], 1);
  }
  __syncthreads();
  if (tid < 256) scn[tid] = hist_s[tid];
  __syncthreads();
  for (int off = 1; off < 256; off <<= 1) {
    int v = (tid < 256 && tid >= off) ? scn[tid - off] : 0;
    __syncthreads();
    if (tid < 256) scn[tid] += v;
    __syncthreads();
  }
  if (tid < 256) {
    int ex = scn[tid] - hist_s[tid];
    lcur[tid] = ex;
    int V = b * 256 + tid;
    if (V < NN) {
      csr_ptr[V] = (int)beg + ex;
      csr_end[V] = (int)beg + scn[tid];
      float dv = rsqrtf((float)(hist_s[tid] + 1));
      dinv[V] = dv;
      dinv_s[tid] = dv;
      int dg = hist_s[tid];
      deg[V] = dg;
      atomicAdd(&dhist[dg > 255 ? 255 : dg], 1);
    }
  }
  __syncthreads();
  for (int i = tid; i < cnt; i += 1024) {
    unsigned int p = pr[i];
    int pos = atomicAdd(&lcur[p >> 16], 1);
    srcb[pos] = (int)(p & 0xFFFFu);
  }
  __syncthreads();
  for (int i = tid; i < cnt; i += 1024) csr_src[beg + i] = srcb[i];

  // x -> bf16 pre-scaled by dinv (row-major)
  for (int i4 = tid; i4 < 256 * 32; i4 += 1024) {
    int vl = i4 >> 5;
    int V = b * 256 + vl;
    if (V < NN) {
      float d = dinv_s[vl];
      int q = i4 & 31;
      f32x4 vx = *((const f32x4*)(x + (size_t)V * DD) + q);
      uint2 o;
      o.x = pack2(vx[0] * d, vx[1] * d);
      o.y = pack2(vx[2] * d, vx[3] * d);
      ((uint2*)(xb + (size_t)V * DD))[q] = o;
    }
  }
}

// ---------------- p3: degree-sorted permutation (tiles get uniform-degree rows) ------
__global__ __launch_bounds__(1024) void p3_k(const int* __restrict__ deg,
                                             const int* __restrict__ dhist,
                                             int* __restrict__ gcur,
                                             int* __restrict__ perm) {
  __shared__ int incl[256], exb[256];
  int tid = threadIdx.x;
  if (tid < 256) incl[tid] = dhist[tid];
  __syncthreads();
  for (int off = 1; off < 256; off <<= 1) {
    int v = (tid < 256 && tid >= off) ? incl[tid - off] : 0;
    __syncthreads();
    if (tid < 256) incl[tid] += v;
    __syncthreads();
  }
  if (tid < 256) exb[tid] = incl[tid] - dhist[tid];
  __syncthreads();
  int i = blockIdx.x * 1024 + tid;
  if (i < NN) {
    int bn = deg[i]; if (bn > 255) bn = 255;
    int pos = exb[bn] + atomicAdd(&gcur[bn], 1);
    perm[pos] = i;
  }
}

// ---------------- fused layer (R4-proven body + degree-uniform tiles via perm) -------
__global__ __launch_bounds__(1024, 8) void flayer_k(
    const unsigned short* __restrict__ hs,
    const unsigned short* __restrict__ Wb,
    const float* __restrict__ bias,
    unsigned short* __restrict__ out,
    const float* __restrict__ dscale,
    const int* __restrict__ csr_ptr,
    const int* __restrict__ csr_end,
    const int* __restrict__ csr_src,
    const float* __restrict__ dinv,
    const int* __restrict__ perm) {
  __shared__ unsigned short Wt[128][136];   // [n][k] bf16, +8 pad (proven pattern)
  __shared__ unsigned short At[16][136];    // aggregated tile [row][k] bf16
  __shared__ int s_vid[16];                 // tile-local row -> node id

  int tid = threadIdx.x;
  for (int i = tid; i < 128 * 16; i += 1024) {
    int rr = i >> 4, c = i & 15;
    *(uint4*)&Wt[rr][c * 8] = *(const uint4*)(Wb + rr * DD + c * 8);
  }

  int wave = tid >> 6, lane = tid & 63;
  int qg = lane >> 4, r = lane & 15;
  int v = perm[blockIdx.x * 16 + wave];    // one dest row per wave (degree-matched)
  if (lane == 0) s_vid[wave] = v;
  const uint4* rows = (const uint4*)hs;

  // ---- aggregation (R4-proven body, verbatim) ----
  float a[8] = {0.f, 0.f, 0.f, 0.f, 0.f, 0.f, 0.f, 0.f};
  float b[8] = {0.f, 0.f, 0.f, 0.f, 0.f, 0.f, 0.f, 0.f};
  if (qg == 0) acc8(a, rows[(size_t)v * 16 + r]);   // self term

  int e = csr_ptr[v] + qg, end = csr_end[v];
  for (; e + 12 < end; e += 16) {
    int s0 = csr_src[e];
    int s1 = csr_src[e + 4];
    int s2 = csr_src[e + 8];
    int s3 = csr_src[e + 12];
    uint4 p0 = rows[(size_t)s0 * 16 + r];
    uint4 p1 = rows[(size_t)s1 * 16 + r];
    uint4 p2 = rows[(size_t)s2 * 16 + r];
    uint4 p3 = rows[(size_t)s3 * 16 + r];
    acc8(a, p0); acc8(b, p1); acc8(a, p2); acc8(b, p3);
  }
  for (; e + 4 < end; e += 8) {
    int s0 = csr_src[e];
    int s1 = csr_src[e + 4];
    uint4 p0 = rows[(size_t)s0 * 16 + r];
    uint4 p1 = rows[(size_t)s1 * 16 + r];
    acc8(a, p0); acc8(b, p1);
  }
  if (e < end) acc8(a, rows[(size_t)csr_src[e] * 16 + r]);

#pragma unroll
  for (int t = 0; t < 8; ++t) a[t] += b[t];
#pragma unroll
  for (int t = 0; t < 8; ++t) {
    a[t] += __shfl_xor(a[t], 16, 64);
    a[t] += __shfl_xor(a[t], 32, 64);
  }

  if (qg == 0) {
    float dv = dinv[v];
    uint4 o;
    o.x = pack2(dv * a[0], dv * a[1]);
    o.y = pack2(dv * a[2], dv * a[3]);
    o.z = pack2(dv * a[4], dv * a[5]);
    o.w = pack2(dv * a[6], dv * a[7]);
    *(uint4*)&At[wave][r * 8] = o;
  }
  __syncthreads();

  // ---- GEMM epilogue: waves 0..7, wave w -> output cols [w*16, w*16+16) ----
  if (wave < 8) {
    short8 afrag[4];
#pragma unroll
    for (int ks = 0; ks < 4; ++ks)
      afrag[ks] = *(const short8*)&At[r][ks * 32 + qg * 8];

    f32x4 acc = (f32x4){0.f, 0.f, 0.f, 0.f};
#pragma unroll
    for (int ks = 0; ks < 4; ++ks) {
      short8 bfrag = *(const short8*)(&Wt[wave * 16 + r][ks * 32 + qg * 8]);
      acc = __builtin_amdgcn_mfma_f32_16x16x32_bf16(afrag[ks], bfrag, acc, 0, 0, 0);
    }

    int coln = wave * 16 + r;
    float bc = bias[coln];
#pragma unroll
    for (int reg = 0; reg < 4; ++reg) {
      int vr = s_vid[qg * 4 + reg];
      float sc = dscale ? dscale[vr] : 1.f;
      float val = fmaxf(acc[reg] + bc, 0.f) * sc;
      out[(size_t)vr * DD + coln] = f2bf(val);
    }
  }
}

// ---------------- fused pool + MLP head (R6-proven, vectorized) ----------------
__global__ __launch_bounds__(512) void poolmlp_k(const unsigned short* __restrict__ h,
                                                 const int* __restrict__ gptr,
                                                 const float* __restrict__ W1,
                                                 const float* __restrict__ b1,
                                                 const float* __restrict__ W2,
                                                 const float* __restrict__ b2,
                                                 const float* __restrict__ W3,
                                                 const float* __restrict__ b3,
                                                 float* __restrict__ out) {
  __shared__ float s_part[8][128];
  __shared__ float s_g[128], s_h1[128], s_h2[64];
  int g = blockIdx.x, tid = threadIdx.x;
  int wave = tid >> 6, lane = tid & 63;
  int qg = lane >> 4, r = lane & 15;
  int beg = gptr[g], end = gptr[g + 1];
  const uint4* rows = (const uint4*)h;

  float A[8] = {0.f, 0.f, 0.f, 0.f, 0.f, 0.f, 0.f, 0.f};
  for (int v = beg + wave * 4 + qg; v < end; v += 32)
    acc8(A, rows[(size_t)v * 16 + r]);
#pragma unroll
  for (int j = 0; j < 8; ++j) {
    A[j] += __shfl_xor(A[j], 16, 64);
    A[j] += __shfl_xor(A[j], 32, 64);
  }
  if (qg == 0) {
    *(f32x4*)&s_part[wave][r * 8]     = (f32x4){A[0], A[1], A[2], A[3]};
    *(f32x4*)&s_part[wave][r * 8 + 4] = (f32x4){A[4], A[5], A[6], A[7]};
  }
  __syncthreads();
  if (tid < 128) {
    float sg = 0.f;
#pragma unroll
    for (int w = 0; w < 8; ++w) sg += s_part[w][tid];
    s_g[tid] = sg;
  }
  __syncthreads();
  if (tid < 128) {
    float a = b1[tid];
    for (int k = 0; k < 128; ++k) a += s_g[k] * W1[k * 128 + tid];
    s_h1[tid] = fmaxf(a, 0.f);
  }
  __syncthreads();
  if (tid < 64) {
    float a = b2[tid];
    for (int k = 0; k < 128; ++k) a += s_h1[k] * W2[k * 64 + tid];
    s_h2[tid] = fmaxf(a, 0.f);
  }
  __syncthreads();
  if (tid < NC) {
    float a = b3[tid];
    for (int k = 0; k < 64; ++k) a += s_h2[k] * W3[k * NC + tid];
    out[g * NC + tid] = a;
  }
}

// ---------------- launch ----------------

extern "C" void kernel_launch(void* const* d_in, const int* in_sizes, int n_in,
                              void* d_out, int out_size, void* d_ws, size_t ws_size,
                              hipStream_t stream) {
  const float* x     = (const float*)d_in[0];
  const int*   ei    = (const int*)d_in[1];
  const int*   batch = (const int*)d_in[2];
  const float* Wc    = (const float*)d_in[3];
  const float* bc    = (const float*)d_in[4];
  const float* W1    = (const float*)d_in[5];
  const float* b1    = (const float*)d_in[6];
  const float* W2    = (const float*)d_in[7];
  const float* b2    = (const float*)d_in[8];
  const float* W3    = (const float*)d_in[9];
  const float* b3    = (const float*)d_in[10];
  float* out = (float*)d_out;

  const int* erow = ei;        // edge_index[0] (source)
  const int* ecol = ei + NE;   // edge_index[1] (dest)

  char* w = (char*)d_ws;
  int*   cursor  = (int*)w;    w += NB * 4;                 // ┐ memset region:
  int*   dhist   = (int*)w;    w += 256 * 4;                // │ NB*4 + 2048 bytes
  int*   gcur    = (int*)w;    w += 256 * 4;                // ┘
  int*   deg     = (int*)w;    w += (size_t)(NN + 4) * 4;
  int*   perm    = (int*)w;    w += (size_t)(NN + 4) * 4;
  int*   csr_ptr = (int*)w;    w += (size_t)(NN + 4) * 4;
  int*   csr_end = (int*)w;    w += (size_t)(NN + 4) * 4;
  int*   gptr    = (int*)w;    w += (NG + 4) * 4;
  int*   csr_src = (int*)w;    w += (size_t)NB * BCAP * 4;  // fixed-base regions
  float* dinv    = (float*)w;  w += (size_t)NN * 4;
  w = (char*)(((uintptr_t)w + 255) & ~(uintptr_t)255);
  unsigned short* Wbt  = (unsigned short*)w; w += (size_t)NL * DD * DD * 2;
  unsigned short* xb   = (unsigned short*)w; w += (size_t)NN * DD * 2;
  unsigned short* hA   = (unsigned short*)w; w += (size_t)NN * DD * 2;
  unsigned short* hB   = (unsigned short*)w; w += (size_t)NN * DD * 2;
  unsigned int* ebuf = (unsigned int*)hA;    // alias: 196*BCAP*4 = 3.96MB < 12.8MB;
                                             // dead before layer-0 writes hA

  hipMemsetAsync(cursor, 0, NB * 4 + 2048, stream);   // cursor + dhist + gcur

  p1b_k<<<NB, 1024, 0, stream>>>(erow, ecol, cursor, ebuf);
  p2_k <<<NB + GPB + NL, 1024, 0, stream>>>(ebuf, cursor, x, batch, Wc, csr_ptr,
                                            csr_end, csr_src, dinv, xb, gptr, Wbt,
                                            deg, dhist);
  p3_k <<<GPB, 1024, 0, stream>>>(deg, dhist, gcur, perm);

  const int fGrid = NN / 16;   // 3125, exact

  for (int l = 0; l < NL; ++l) {
    const unsigned short* hin = (l == 0) ? xb : ((l & 1) ? hA : hB);
    unsigned short* dst = (l & 1) ? hB : hA;
    const float* dsc = (l == NL - 1) ? nullptr : dinv;
    flayer_k<<<fGrid, 1024, 0, stream>>>(hin, Wbt + (size_t)l * DD * DD,
                                         bc + (size_t)l * DD, dst, dsc,
                                         csr_ptr, csr_end, csr_src, dinv, perm);
  }

  poolmlp_k<<<NG, 512, 0, stream>>>(hB, gptr, W1, b1, W2, b2, W3, b3, out);

  (void)in_sizes; (void)n_in; (void)out_size; (void)ws_size;
}

// Round 10
// 300.633 us; speedup vs baseline: 2.8434x; 2.0023x over previous
//
#include <hip/hip_runtime.h>
#include <stdint.h>
#include <stddef.h>

#define NN 50000
#define NE 800000
#define DD 128
#define NL 4
#define NG 512
#define NC 10
#define NB 196           // buckets of 256 dest nodes: ceil(50000/256)
#define BCAP 5056        // fixed per-bucket region capacity (mean 4081, huge margin)
#define GPB 49           // p2 extra blocks for gptr: ceil(50000/1024)

using short8 = __attribute__((ext_vector_type(8))) short;
using f32x4  = __attribute__((ext_vector_type(4))) float;

__device__ __forceinline__ float bf2f(unsigned short u) {
  union { unsigned int i; float f; } c; c.i = ((unsigned int)u) << 16; return c.f;
}
__device__ __forceinline__ unsigned short f2bf(float f) {
  union { unsigned int i; float f; } c; c.f = f;
  unsigned int i = c.i;
  return (unsigned short)((i + 0x7FFFu + ((i >> 16) & 1u)) >> 16);
}
__device__ __forceinline__ unsigned int pack2(float a, float b) {
  return (unsigned int)f2bf(a) | ((unsigned int)f2bf(b) << 16);
}
__device__ __forceinline__ void acc8(float* a, uint4 p) {
  a[0] += bf2f((unsigned short)(p.x & 0xffffu)); a[1] += bf2f((unsigned short)(p.x >> 16));
  a[2] += bf2f((unsigned short)(p.y & 0xffffu)); a[3] += bf2f((unsigned short)(p.y >> 16));
  a[4] += bf2f((unsigned short)(p.z & 0xffffu)); a[5] += bf2f((unsigned short)(p.z >> 16));
  a[6] += bf2f((unsigned short)(p.w & 0xffffu)); a[7] += bf2f((unsigned short)(p.w >> 16));
}

// ---------------- p1b v2: place packed edges into FIXED bucket regions.
// LDS-staged, bucket-ordered global writes (R6-proven).
__global__ __launch_bounds__(1024) void p1b_k(const int* __restrict__ erow,
                                              const int* __restrict__ ecol,
                                              int* __restrict__ cursor,
                                              unsigned int* __restrict__ ebuf) {
  __shared__ int lcnt[256], loff[256];    // 196 used, padded to 256 for the scan
  __shared__ int gb[NB];
  __shared__ unsigned int stage[4096];
  __shared__ int gpos[4096];
  int tid = threadIdx.x;
  if (tid < 256) lcnt[tid] = 0;
  __syncthreads();
  int e0 = blockIdx.x * 4096 + tid;
  int bk[4], sl[4]; unsigned int pk[4];
#pragma unroll
  for (int j = 0; j < 4; ++j) {
    int e = e0 + j * 1024;
    bk[j] = -1;
    if (e < NE) {
      int d = ecol[e], s = erow[e];
      bk[j] = d >> 8;
      pk[j] = ((unsigned int)(d & 255) << 16) | (unsigned int)s;
      sl[j] = atomicAdd(&lcnt[bk[j]], 1);
    }
  }
  __syncthreads();
  if (tid < 256) loff[tid] = lcnt[tid];
  __syncthreads();
  for (int off = 1; off < 256; off <<= 1) {
    int v = (tid < 256 && tid >= off) ? loff[tid - off] : 0;
    __syncthreads();
    if (tid < 256) loff[tid] += v;
    __syncthreads();
  }
  if (tid < NB) {
    int c = lcnt[tid];
    gb[tid] = c ? atomicAdd(&cursor[tid], c) : 0;
  }
  __syncthreads();
#pragma unroll
  for (int j = 0; j < 4; ++j)
    if (bk[j] >= 0) {
      int ex = loff[bk[j]] - lcnt[bk[j]] + sl[j];
      stage[ex] = pk[j];
      gpos[ex] = bk[j] * BCAP + gb[bk[j]] + sl[j];
    }
  __syncthreads();
  int total = loff[255];
  for (int i = tid; i < total; i += 1024)
    ebuf[gpos[i]] = stage[i];
}

// ---------------- p2 (R6-proven): bucket counting sort + dinv + x->bf16*dinv | gptr | W^T ----
__global__ __launch_bounds__(1024) void p2_k(const unsigned int* __restrict__ ebuf,
                                             const int* __restrict__ cursor,
                                             const float* __restrict__ x,
                                             const int* __restrict__ batch,
                                             const float* __restrict__ Wc,
                                             int* __restrict__ csr_ptr,
                                             int* __restrict__ csr_end,
                                             int* __restrict__ csr_src,
                                             float* __restrict__ dinv,
                                             unsigned short* __restrict__ xb,
                                             int* __restrict__ gptr,
                                             unsigned short* __restrict__ Wbt) {
  int b = blockIdx.x, tid = threadIdx.x;
  if (b >= NB + GPB) {                   // W conversion role
    int l = b - NB - GPB;
    const float* W = Wc + (size_t)l * DD * DD;
    unsigned short* WT = Wbt + (size_t)l * DD * DD;
    for (int i = tid; i < DD * DD; i += 1024) {
      int n = i >> 7, k = i & 127;
      WT[n * DD + k] = f2bf(W[k * DD + n]);
    }
    return;
  }
  if (b >= NB) {                         // gptr role
    int i = (b - NB) * 1024 + tid;
    if (i >= NN) return;
    int bb = batch[i];
    int bp = (i == 0) ? -1 : batch[i - 1];
    for (int g = bp + 1; g <= bb; ++g) gptr[g] = i;
    if (i == NN - 1) { for (int g = bb + 1; g <= NG; ++g) gptr[g] = NN; }
    return;
  }

  __shared__ unsigned int pr[BCAP];
  __shared__ int srcb[BCAP];
  __shared__ int hist_s[256], scn[256], lcur[256];
  __shared__ float dinv_s[256];
  size_t beg = (size_t)b * BCAP;
  int cnt = cursor[b];
  if (cnt > BCAP) cnt = BCAP;            // safety (never hit)

  if (tid < 256) hist_s[tid] = 0;
  __syncthreads();
  for (int i = tid; i < cnt; i += 1024) {
    unsigned int p = ebuf[beg + i];
    pr[i] = p;
    atomicAdd(&hist_s[p >> 16], 1);
  }
  __syncthreads();
  if (tid < 256) scn[tid] = hist_s[tid];
  __syncthreads();
  for (int off = 1; off < 256; off <<= 1) {
    int v = (tid < 256 && tid >= off) ? scn[tid - off] : 0;
    __syncthreads();
    if (tid < 256) scn[tid] += v;
    __syncthreads();
  }
  if (tid < 256) {
    int ex = scn[tid] - hist_s[tid];
    lcur[tid] = ex;
    int V = b * 256 + tid;
    if (V < NN) {
      csr_ptr[V] = (int)beg + ex;
      csr_end[V] = (int)beg + scn[tid];
      float dv = rsqrtf((float)(hist_s[tid] + 1));
      dinv[V] = dv;
      dinv_s[tid] = dv;
    }
  }
  __syncthreads();
  for (int i = tid; i < cnt; i += 1024) {
    unsigned int p = pr[i];
    int pos = atomicAdd(&lcur[p >> 16], 1);
    srcb[pos] = (int)(p & 0xFFFFu);
  }
  __syncthreads();
  for (int i = tid; i < cnt; i += 1024) csr_src[beg + i] = srcb[i];

  // x -> bf16 pre-scaled by dinv (row-major)
  for (int i4 = tid; i4 < 256 * 32; i4 += 1024) {
    int vl = i4 >> 5;
    int V = b * 256 + vl;
    if (V < NN) {
      float d = dinv_s[vl];
      int q = i4 & 31;
      f32x4 vx = *((const f32x4*)(x + (size_t)V * DD) + q);
      uint2 o;
      o.x = pack2(vx[0] * d, vx[1] * d);
      o.y = pack2(vx[2] * d, vx[3] * d);
      ((uint2*)(xb + (size_t)V * DD))[q] = o;
    }
  }
}

// ---------------- fused layer (R4-proven): 16 waves, ONE dest row per wave,
// 8-wave MFMA epilogue on the 16-row LDS tile. 50000 = 3125 * 16 exactly.
__global__ __launch_bounds__(1024, 8) void flayer_k(
    const unsigned short* __restrict__ hs,
    const unsigned short* __restrict__ Wb,
    const float* __restrict__ bias,
    unsigned short* __restrict__ out,
    const float* __restrict__ dscale,
    const int* __restrict__ csr_ptr,
    const int* __restrict__ csr_end,
    const int* __restrict__ csr_src,
    const float* __restrict__ dinv) {
  __shared__ unsigned short Wt[128][136];   // [n][k] bf16, +8 pad (proven pattern)
  __shared__ unsigned short At[16][136];    // aggregated tile [row][k] bf16

  int tid = threadIdx.x;
  for (int i = tid; i < 128 * 16; i += 1024) {
    int rr = i >> 4, c = i & 15;
    *(uint4*)&Wt[rr][c * 8] = *(const uint4*)(Wb + rr * DD + c * 8);
  }

  int wave = tid >> 6, lane = tid & 63;
  int qg = lane >> 4, r = lane & 15;
  int v = blockIdx.x * 16 + wave;          // one dest row per wave; always < NN
  const uint4* rows = (const uint4*)hs;

  // ---- aggregation (agg_k proven body, verbatim) ----
  float a[8] = {0.f, 0.f, 0.f, 0.f, 0.f, 0.f, 0.f, 0.f};
  float b[8] = {0.f, 0.f, 0.f, 0.f, 0.f, 0.f, 0.f, 0.f};
  if (qg == 0) acc8(a, rows[(size_t)v * 16 + r]);   // self term

  int e = csr_ptr[v] + qg, end = csr_end[v];
  for (; e + 12 < end; e += 16) {
    int s0 = csr_src[e];
    int s1 = csr_src[e + 4];
    int s2 = csr_src[e + 8];
    int s3 = csr_src[e + 12];
    uint4 p0 = rows[(size_t)s0 * 16 + r];
    uint4 p1 = rows[(size_t)s1 * 16 + r];
    uint4 p2 = rows[(size_t)s2 * 16 + r];
    uint4 p3 = rows[(size_t)s3 * 16 + r];
    acc8(a, p0); acc8(b, p1); acc8(a, p2); acc8(b, p3);
  }
  for (; e + 4 < end; e += 8) {
    int s0 = csr_src[e];
    int s1 = csr_src[e + 4];
    uint4 p0 = rows[(size_t)s0 * 16 + r];
    uint4 p1 = rows[(size_t)s1 * 16 + r];
    acc8(a, p0); acc8(b, p1);
  }
  if (e < end) acc8(a, rows[(size_t)csr_src[e] * 16 + r]);

#pragma unroll
  for (int t = 0; t < 8; ++t) a[t] += b[t];
#pragma unroll
  for (int t = 0; t < 8; ++t) {
    a[t] += __shfl_xor(a[t], 16, 64);
    a[t] += __shfl_xor(a[t], 32, 64);
  }

  if (qg == 0) {
    float dv = dinv[v];
    uint4 o;
    o.x = pack2(dv * a[0], dv * a[1]);
    o.y = pack2(dv * a[2], dv * a[3]);
    o.z = pack2(dv * a[4], dv * a[5]);
    o.w = pack2(dv * a[6], dv * a[7]);
    *(uint4*)&At[wave][r * 8] = o;
  }
  __syncthreads();

  // ---- GEMM epilogue: waves 0..7, wave w -> output cols [w*16, w*16+16) ----
  if (wave < 8) {
    short8 afrag[4];
#pragma unroll
    for (int ks = 0; ks < 4; ++ks)
      afrag[ks] = *(const short8*)&At[r][ks * 32 + qg * 8];

    f32x4 acc = (f32x4){0.f, 0.f, 0.f, 0.f};
#pragma unroll
    for (int ks = 0; ks < 4; ++ks) {
      short8 bfrag = *(const short8*)(&Wt[wave * 16 + r][ks * 32 + qg * 8]);
      acc = __builtin_amdgcn_mfma_f32_16x16x32_bf16(afrag[ks], bfrag, acc, 0, 0, 0);
    }

    int orow = blockIdx.x * 16 + qg * 4;
    int coln = wave * 16 + r;
    float bc = bias[coln];
#pragma unroll
    for (int reg = 0; reg < 4; ++reg) {
      int rr = orow + reg;
      float sc = dscale ? dscale[rr] : 1.f;
      float val = fmaxf(acc[reg] + bc, 0.f) * sc;
      out[(size_t)rr * DD + coln] = f2bf(val);
    }
  }
}

// ---------------- fused pool + MLP head v2: 512 threads, 4 rows in flight ----------------
__global__ __launch_bounds__(512) void poolmlp_k(const unsigned short* __restrict__ h,
                                                 const int* __restrict__ gptr,
                                                 const float* __restrict__ W1,
                                                 const float* __restrict__ b1,
                                                 const float* __restrict__ W2,
                                                 const float* __restrict__ b2,
                                                 const float* __restrict__ W3,
                                                 const float* __restrict__ b3,
                                                 float* __restrict__ out) {
  __shared__ float s_part[4][128];
  __shared__ float s_g[128], s_h1[128], s_h2[64];
  int g = blockIdx.x, tid = threadIdx.x;
  int j = tid >> 7, t = tid & 127;
  int beg = gptr[g], end = gptr[g + 1];
  float acc = 0.f;
  for (int v = beg + j; v < end; v += 4) acc += bf2f(h[(size_t)v * DD + t]);
  s_part[j][t] = acc;
  __syncthreads();
  if (tid < 128) {
    s_g[t] = s_part[0][t] + s_part[1][t] + s_part[2][t] + s_part[3][t];
  }
  __syncthreads();
  if (tid < 128) {
    float a = b1[t];
    for (int k = 0; k < 128; ++k) a += s_g[k] * W1[k * 128 + t];
    s_h1[t] = fmaxf(a, 0.f);
  }
  __syncthreads();
  if (tid < 64) {
    float a = b2[t];
    for (int k = 0; k < 128; ++k) a += s_h1[k] * W2[k * 64 + t];
    s_h2[t] = fmaxf(a, 0.f);
  }
  __syncthreads();
  if (tid < NC) {
    float a = b3[t];
    for (int k = 0; k < 64; ++k) a += s_h2[k] * W3[k * NC + t];
    out[g * NC + t] = a;
  }
}

// ---------------- launch ----------------

extern "C" void kernel_launch(void* const* d_in, const int* in_sizes, int n_in,
                              void* d_out, int out_size, void* d_ws, size_t ws_size,
                              hipStream_t stream) {
  const float* x     = (const float*)d_in[0];
  const int*   ei    = (const int*)d_in[1];
  const int*   batch = (const int*)d_in[2];
  const float* Wc    = (const float*)d_in[3];
  const float* bc    = (const float*)d_in[4];
  const float* W1    = (const float*)d_in[5];
  const float* b1    = (const float*)d_in[6];
  const float* W2    = (const float*)d_in[7];
  const float* b2    = (const float*)d_in[8];
  const float* W3    = (const float*)d_in[9];
  const float* b3    = (const float*)d_in[10];
  float* out = (float*)d_out;

  const int* erow = ei;        // edge_index[0] (source)
  const int* ecol = ei + NE;   // edge_index[1] (dest)

  char* w = (char*)d_ws;
  int*   cursor  = (int*)w;    w += NB * 4;                 // memset 0 (784 B)
  int*   csr_ptr = (int*)w;    w += (size_t)(NN + 4) * 4;
  int*   csr_end = (int*)w;    w += (size_t)(NN + 4) * 4;
  int*   gptr    = (int*)w;    w += (NG + 4) * 4;
  int*   csr_src = (int*)w;    w += (size_t)NB * BCAP * 4;  // fixed-base regions
  float* dinv    = (float*)w;  w += (size_t)NN * 4;
  w = (char*)(((uintptr_t)w + 255) & ~(uintptr_t)255);
  unsigned short* Wbt  = (unsigned short*)w; w += (size_t)NL * DD * DD * 2;
  unsigned short* xb   = (unsigned short*)w; w += (size_t)NN * DD * 2;
  unsigned short* hA   = (unsigned short*)w; w += (size_t)NN * DD * 2;
  unsigned short* hB   = (unsigned short*)w; w += (size_t)NN * DD * 2;
  unsigned int* ebuf = (unsigned int*)hA;    // alias: 196*BCAP*4 = 3.96MB < 12.8MB;
                                             // dead before layer-0 writes hA

  hipMemsetAsync(cursor, 0, NB * 4, stream);

  p1b_k<<<NB, 1024, 0, stream>>>(erow, ecol, cursor, ebuf);
  p2_k <<<NB + GPB + NL, 1024, 0, stream>>>(ebuf, cursor, x, batch, Wc, csr_ptr,
                                            csr_end, csr_src, dinv, xb, gptr, Wbt);

  const int fGrid = NN / 16;   // 3125, exact

  for (int l = 0; l < NL; ++l) {
    const unsigned short* hin = (l == 0) ? xb : ((l & 1) ? hA : hB);
    unsigned short* dst = (l & 1) ? hB : hA;
    const float* dsc = (l == NL - 1) ? nullptr : dinv;
    flayer_k<<<fGrid, 1024, 0, stream>>>(hin, Wbt + (size_t)l * DD * DD,
                                         bc + (size_t)l * DD, dst, dsc,
                                         csr_ptr, csr_end, csr_src, dinv);
  }

  poolmlp_k<<<NG, 512, 0, stream>>>(hB, gptr, W1, b1, W2, b2, W3, b3, out);

  (void)in_sizes; (void)n_in; (void)out_size; (void)ws_size;
}

// Round 11
// 300.312 us; speedup vs baseline: 2.8464x; 1.0011x over previous
//
#include <hip/hip_runtime.h>
#include <stdint.h>
#include <stddef.h>

#define NN 50000
#define NE 800000
#define DD 128
#define NL 4
#define NG 512
#define NC 10
#define NB 196           // buckets of 256 dest nodes: ceil(50000/256)
#define BCAP 5056        // fixed per-bucket region capacity (mean 4081, huge margin)
#define GPB 49           // p2 extra blocks for gptr: ceil(50000/1024)
#define P1G 391          // p1b grid: ceil(800000/2048) -> all 256 CUs covered

using short8 = __attribute__((ext_vector_type(8))) short;
using f32x4  = __attribute__((ext_vector_type(4))) float;

__device__ __forceinline__ float bf2f(unsigned short u) {
  union { unsigned int i; float f; } c; c.i = ((unsigned int)u) << 16; return c.f;
}
__device__ __forceinline__ unsigned short f2bf(float f) {
  union { unsigned int i; float f; } c; c.f = f;
  unsigned int i = c.i;
  return (unsigned short)((i + 0x7FFFu + ((i >> 16) & 1u)) >> 16);
}
__device__ __forceinline__ unsigned int pack2(float a, float b) {
  return (unsigned int)f2bf(a) | ((unsigned int)f2bf(b) << 16);
}
__device__ __forceinline__ void acc8(float* a, uint4 p) {
  a[0] += bf2f((unsigned short)(p.x & 0xffffu)); a[1] += bf2f((unsigned short)(p.x >> 16));
  a[2] += bf2f((unsigned short)(p.y & 0xffffu)); a[3] += bf2f((unsigned short)(p.y >> 16));
  a[4] += bf2f((unsigned short)(p.z & 0xffffu)); a[5] += bf2f((unsigned short)(p.z >> 16));
  a[6] += bf2f((unsigned short)(p.w & 0xffffu)); a[7] += bf2f((unsigned short)(p.w >> 16));
}

// ---------------- p1b v3: LDS-staged bucket-ordered edge placement, 2048 edges/block
// (391 blocks -> full CU coverage; R6's 196x4096 left 60 CUs idle).
__global__ __launch_bounds__(1024) void p1b_k(const int* __restrict__ erow,
                                              const int* __restrict__ ecol,
                                              int* __restrict__ cursor,
                                              unsigned int* __restrict__ ebuf) {
  __shared__ int lcnt[256], loff[256];    // 196 used, padded to 256 for the scan
  __shared__ int gb[NB];
  __shared__ unsigned int stage[2048];
  __shared__ int gpos[2048];
  int tid = threadIdx.x;
  if (tid < 256) lcnt[tid] = 0;
  __syncthreads();
  int e0 = blockIdx.x * 2048 + tid;
  int bk[2], sl[2]; unsigned int pk[2];
#pragma unroll
  for (int j = 0; j < 2; ++j) {
    int e = e0 + j * 1024;
    bk[j] = -1;
    if (e < NE) {
      int d = ecol[e], s = erow[e];
      bk[j] = d >> 8;
      pk[j] = ((unsigned int)(d & 255) << 16) | (unsigned int)s;
      sl[j] = atomicAdd(&lcnt[bk[j]], 1);
    }
  }
  __syncthreads();
  if (tid < 256) loff[tid] = lcnt[tid];
  __syncthreads();
  for (int off = 1; off < 256; off <<= 1) {
    int v = (tid < 256 && tid >= off) ? loff[tid - off] : 0;
    __syncthreads();
    if (tid < 256) loff[tid] += v;
    __syncthreads();
  }
  if (tid < NB) {
    int c = lcnt[tid];
    gb[tid] = c ? atomicAdd(&cursor[tid], c) : 0;
  }
  __syncthreads();
#pragma unroll
  for (int j = 0; j < 2; ++j)
    if (bk[j] >= 0) {
      int ex = loff[bk[j]] - lcnt[bk[j]] + sl[j];
      stage[ex] = pk[j];
      gpos[ex] = bk[j] * BCAP + gb[bk[j]] + sl[j];
    }
  __syncthreads();
  int total = loff[255];
  for (int i = tid; i < total; i += 1024)
    ebuf[gpos[i]] = stage[i];
}

// ---------------- p2 (R6-proven): bucket counting sort + dinv + x->bf16*dinv | gptr | W^T ----
__global__ __launch_bounds__(1024) void p2_k(const unsigned int* __restrict__ ebuf,
                                             const int* __restrict__ cursor,
                                             const float* __restrict__ x,
                                             const int* __restrict__ batch,
                                             const float* __restrict__ Wc,
                                             int* __restrict__ csr_ptr,
                                             int* __restrict__ csr_end,
                                             int* __restrict__ csr_src,
                                             float* __restrict__ dinv,
                                             unsigned short* __restrict__ xb,
                                             int* __restrict__ gptr,
                                             unsigned short* __restrict__ Wbt) {
  int b = blockIdx.x, tid = threadIdx.x;
  if (b >= NB + GPB) {                   // W conversion role
    int l = b - NB - GPB;
    const float* W = Wc + (size_t)l * DD * DD;
    unsigned short* WT = Wbt + (size_t)l * DD * DD;
    for (int i = tid; i < DD * DD; i += 1024) {
      int n = i >> 7, k = i & 127;
      WT[n * DD + k] = f2bf(W[k * DD + n]);
    }
    return;
  }
  if (b >= NB) {                         // gptr role
    int i = (b - NB) * 1024 + tid;
    if (i >= NN) return;
    int bb = batch[i];
    int bp = (i == 0) ? -1 : batch[i - 1];
    for (int g = bp + 1; g <= bb; ++g) gptr[g] = i;
    if (i == NN - 1) { for (int g = bb + 1; g <= NG; ++g) gptr[g] = NN; }
    return;
  }

  __shared__ unsigned int pr[BCAP];
  __shared__ int srcb[BCAP];
  __shared__ int hist_s[256], scn[256], lcur[256];
  __shared__ float dinv_s[256];
  size_t beg = (size_t)b * BCAP;
  int cnt = cursor[b];
  if (cnt > BCAP) cnt = BCAP;            // safety (never hit)

  if (tid < 256) hist_s[tid] = 0;
  __syncthreads();
  for (int i = tid; i < cnt; i += 1024) {
    unsigned int p = ebuf[beg + i];
    pr[i] = p;
    atomicAdd(&hist_s[p >> 16], 1);
  }
  __syncthreads();
  if (tid < 256) scn[tid] = hist_s[tid];
  __syncthreads();
  for (int off = 1; off < 256; off <<= 1) {
    int v = (tid < 256 && tid >= off) ? scn[tid - off] : 0;
    __syncthreads();
    if (tid < 256) scn[tid] += v;
    __syncthreads();
  }
  if (tid < 256) {
    int ex = scn[tid] - hist_s[tid];
    lcur[tid] = ex;
    int V = b * 256 + tid;
    if (V < NN) {
      csr_ptr[V] = (int)beg + ex;
      csr_end[V] = (int)beg + scn[tid];
      float dv = rsqrtf((float)(hist_s[tid] + 1));
      dinv[V] = dv;
      dinv_s[tid] = dv;
    }
  }
  __syncthreads();
  for (int i = tid; i < cnt; i += 1024) {
    unsigned int p = pr[i];
    int pos = atomicAdd(&lcur[p >> 16], 1);
    srcb[pos] = (int)(p & 0xFFFFu);
  }
  __syncthreads();
  for (int i = tid; i < cnt; i += 1024) csr_src[beg + i] = srcb[i];

  // x -> bf16 pre-scaled by dinv (row-major)
  for (int i4 = tid; i4 < 256 * 32; i4 += 1024) {
    int vl = i4 >> 5;
    int V = b * 256 + vl;
    if (V < NN) {
      float d = dinv_s[vl];
      int q = i4 & 31;
      f32x4 vx = *((const f32x4*)(x + (size_t)V * DD) + q);
      uint2 o;
      o.x = pack2(vx[0] * d, vx[1] * d);
      o.y = pack2(vx[2] * d, vx[3] * d);
      ((uint2*)(xb + (size_t)V * DD))[q] = o;
    }
  }
}

// ---------------- fused layer (R4-proven): 16 waves, ONE dest row per wave,
// 8-wave MFMA epilogue on the 16-row LDS tile. 50000 = 3125 * 16 exactly.
__global__ __launch_bounds__(1024, 8) void flayer_k(
    const unsigned short* __restrict__ hs,
    const unsigned short* __restrict__ Wb,
    const float* __restrict__ bias,
    unsigned short* __restrict__ out,
    const float* __restrict__ dscale,
    const int* __restrict__ csr_ptr,
    const int* __restrict__ csr_end,
    const int* __restrict__ csr_src,
    const float* __restrict__ dinv) {
  __shared__ unsigned short Wt[128][136];   // [n][k] bf16, +8 pad (proven pattern)
  __shared__ unsigned short At[16][136];    // aggregated tile [row][k] bf16

  int tid = threadIdx.x;
  for (int i = tid; i < 128 * 16; i += 1024) {
    int rr = i >> 4, c = i & 15;
    *(uint4*)&Wt[rr][c * 8] = *(const uint4*)(Wb + rr * DD + c * 8);
  }

  int wave = tid >> 6, lane = tid & 63;
  int qg = lane >> 4, r = lane & 15;
  int v = blockIdx.x * 16 + wave;          // one dest row per wave; always < NN
  const uint4* rows = (const uint4*)hs;

  // ---- aggregation (agg_k proven body, verbatim) ----
  float a[8] = {0.f, 0.f, 0.f, 0.f, 0.f, 0.f, 0.f, 0.f};
  float b[8] = {0.f, 0.f, 0.f, 0.f, 0.f, 0.f, 0.f, 0.f};
  if (qg == 0) acc8(a, rows[(size_t)v * 16 + r]);   // self term

  int e = csr_ptr[v] + qg, end = csr_end[v];
  for (; e + 12 < end; e += 16) {
    int s0 = csr_src[e];
    int s1 = csr_src[e + 4];
    int s2 = csr_src[e + 8];
    int s3 = csr_src[e + 12];
    uint4 p0 = rows[(size_t)s0 * 16 + r];
    uint4 p1 = rows[(size_t)s1 * 16 + r];
    uint4 p2 = rows[(size_t)s2 * 16 + r];
    uint4 p3 = rows[(size_t)s3 * 16 + r];
    acc8(a, p0); acc8(b, p1); acc8(a, p2); acc8(b, p3);
  }
  for (; e + 4 < end; e += 8) {
    int s0 = csr_src[e];
    int s1 = csr_src[e + 4];
    uint4 p0 = rows[(size_t)s0 * 16 + r];
    uint4 p1 = rows[(size_t)s1 * 16 + r];
    acc8(a, p0); acc8(b, p1);
  }
  if (e < end) acc8(a, rows[(size_t)csr_src[e] * 16 + r]);

#pragma unroll
  for (int t = 0; t < 8; ++t) a[t] += b[t];
#pragma unroll
  for (int t = 0; t < 8; ++t) {
    a[t] += __shfl_xor(a[t], 16, 64);
    a[t] += __shfl_xor(a[t], 32, 64);
  }

  if (qg == 0) {
    float dv = dinv[v];
    uint4 o;
    o.x = pack2(dv * a[0], dv * a[1]);
    o.y = pack2(dv * a[2], dv * a[3]);
    o.z = pack2(dv * a[4], dv * a[5]);
    o.w = pack2(dv * a[6], dv * a[7]);
    *(uint4*)&At[wave][r * 8] = o;
  }
  __syncthreads();

  // ---- GEMM epilogue: waves 0..7, wave w -> output cols [w*16, w*16+16) ----
  if (wave < 8) {
    short8 afrag[4];
#pragma unroll
    for (int ks = 0; ks < 4; ++ks)
      afrag[ks] = *(const short8*)&At[r][ks * 32 + qg * 8];

    f32x4 acc = (f32x4){0.f, 0.f, 0.f, 0.f};
#pragma unroll
    for (int ks = 0; ks < 4; ++ks) {
      short8 bfrag = *(const short8*)(&Wt[wave * 16 + r][ks * 32 + qg * 8]);
      acc = __builtin_amdgcn_mfma_f32_16x16x32_bf16(afrag[ks], bfrag, acc, 0, 0, 0);
    }

    int orow = blockIdx.x * 16 + qg * 4;
    int coln = wave * 16 + r;
    float bc = bias[coln];
#pragma unroll
    for (int reg = 0; reg < 4; ++reg) {
      int rr = orow + reg;
      float sc = dscale ? dscale[rr] : 1.f;
      float val = fmaxf(acc[reg] + bc, 0.f) * sc;
      out[(size_t)rr * DD + coln] = f2bf(val);
    }
  }
}

// ---------------- fused pool + MLP head v3: uint4-vectorized pooling (16B/lane) -------
__global__ __launch_bounds__(512) void poolmlp_k(const unsigned short* __restrict__ h,
                                                 const int* __restrict__ gptr,
                                                 const float* __restrict__ W1,
                                                 const float* __restrict__ b1,
                                                 const float* __restrict__ W2,
                                                 const float* __restrict__ b2,
                                                 const float* __restrict__ W3,
                                                 const float* __restrict__ b3,
                                                 float* __restrict__ out) {
  __shared__ float s_part[8][128];
  __shared__ float s_g[128], s_h1[128], s_h2[64];
  int g = blockIdx.x, tid = threadIdx.x;
  int wave = tid >> 6, lane = tid & 63;
  int qg = lane >> 4, r = lane & 15;
  int beg = gptr[g], end = gptr[g + 1];
  const uint4* rows = (const uint4*)h;

  float A[8] = {0.f, 0.f, 0.f, 0.f, 0.f, 0.f, 0.f, 0.f};
  for (int v = beg + wave * 4 + qg; v < end; v += 32)
    acc8(A, rows[(size_t)v * 16 + r]);
#pragma unroll
  for (int j = 0; j < 8; ++j) {
    A[j] += __shfl_xor(A[j], 16, 64);
    A[j] += __shfl_xor(A[j], 32, 64);
  }
  if (qg == 0) {
    *(f32x4*)&s_part[wave][r * 8]     = (f32x4){A[0], A[1], A[2], A[3]};
    *(f32x4*)&s_part[wave][r * 8 + 4] = (f32x4){A[4], A[5], A[6], A[7]};
  }
  __syncthreads();
  if (tid < 128) {
    float sg = 0.f;
#pragma unroll
    for (int w = 0; w < 8; ++w) sg += s_part[w][tid];
    s_g[tid] = sg;
  }
  __syncthreads();
  if (tid < 128) {
    float a = b1[tid];
    for (int k = 0; k < 128; ++k) a += s_g[k] * W1[k * 128 + tid];
    s_h1[tid] = fmaxf(a, 0.f);
  }
  __syncthreads();
  if (tid < 64) {
    float a = b2[tid];
    for (int k = 0; k < 128; ++k) a += s_h1[k] * W2[k * 64 + tid];
    s_h2[tid] = fmaxf(a, 0.f);
  }
  __syncthreads();
  if (tid < NC) {
    float a = b3[tid];
    for (int k = 0; k < 64; ++k) a += s_h2[k] * W3[k * NC + tid];
    out[g * NC + tid] = a;
  }
}

// ---------------- launch ----------------

extern "C" void kernel_launch(void* const* d_in, const int* in_sizes, int n_in,
                              void* d_out, int out_size, void* d_ws, size_t ws_size,
                              hipStream_t stream) {
  const float* x     = (const float*)d_in[0];
  const int*   ei    = (const int*)d_in[1];
  const int*   batch = (const int*)d_in[2];
  const float* Wc    = (const float*)d_in[3];
  const float* bc    = (const float*)d_in[4];
  const float* W1    = (const float*)d_in[5];
  const float* b1    = (const float*)d_in[6];
  const float* W2    = (const float*)d_in[7];
  const float* b2    = (const float*)d_in[8];
  const float* W3    = (const float*)d_in[9];
  const float* b3    = (const float*)d_in[10];
  float* out = (float*)d_out;

  const int* erow = ei;        // edge_index[0] (source)
  const int* ecol = ei + NE;   // edge_index[1] (dest)

  char* w = (char*)d_ws;
  int*   cursor  = (int*)w;    w += NB * 4;                 // memset 0 (784 B)
  int*   csr_ptr = (int*)w;    w += (size_t)(NN + 4) * 4;
  int*   csr_end = (int*)w;    w += (size_t)(NN + 4) * 4;
  int*   gptr    = (int*)w;    w += (NG + 4) * 4;
  int*   csr_src = (int*)w;    w += (size_t)NB * BCAP * 4;  // fixed-base regions
  float* dinv    = (float*)w;  w += (size_t)NN * 4;
  w = (char*)(((uintptr_t)w + 255) & ~(uintptr_t)255);
  unsigned short* Wbt  = (unsigned short*)w; w += (size_t)NL * DD * DD * 2;
  unsigned short* xb   = (unsigned short*)w; w += (size_t)NN * DD * 2;
  unsigned short* hA   = (unsigned short*)w; w += (size_t)NN * DD * 2;
  unsigned short* hB   = (unsigned short*)w; w += (size_t)NN * DD * 2;
  unsigned int* ebuf = (unsigned int*)hA;    // alias: 196*BCAP*4 = 3.96MB < 12.8MB;
                                             // dead before layer-0 writes hA

  hipMemsetAsync(cursor, 0, NB * 4, stream);

  p1b_k<<<P1G, 1024, 0, stream>>>(erow, ecol, cursor, ebuf);
  p2_k <<<NB + GPB + NL, 1024, 0, stream>>>(ebuf, cursor, x, batch, Wc, csr_ptr,
                                            csr_end, csr_src, dinv, xb, gptr, Wbt);

  const int fGrid = NN / 16;   // 3125, exact

  for (int l = 0; l < NL; ++l) {
    const unsigned short* hin = (l == 0) ? xb : ((l & 1) ? hA : hB);
    unsigned short* dst = (l & 1) ? hB : hA;
    const float* dsc = (l == NL - 1) ? nullptr : dinv;
    flayer_k<<<fGrid, 1024, 0, stream>>>(hin, Wbt + (size_t)l * DD * DD,
                                         bc + (size_t)l * DD, dst, dsc,
                                         csr_ptr, csr_end, csr_src, dinv);
  }

  poolmlp_k<<<NG, 512, 0, stream>>>(hB, gptr, W1, b1, W2, b2, W3, b3, out);

  (void)in_sizes; (void)n_in; (void)out_size; (void)ws_size;
}